// Round 4
// baseline (541.228 us; speedup 1.0000x reference)
//
#include <hip/hip_runtime.h>
#include <hip/hip_bf16.h>
#include <math.h>

#define T_SEQ 4096
#define HIDDEN 2048
#define NH 16
#define NKV 2
#define HD 128
#define GQ (NH / NKV)
#define QKV_N 2560
#define ROPE_THETA 10000.0f

using bf16 = __hip_bfloat16;
typedef __attribute__((ext_vector_type(8))) short short8;
typedef __attribute__((ext_vector_type(4))) float float4v;
typedef __attribute__((ext_vector_type(16))) float float16v;

// ---------------------------------------------------------------- helpers

__device__ __forceinline__ void gload_lds16(const void* g, void* l) {
  __builtin_amdgcn_global_load_lds(
      (const __attribute__((address_space(1))) unsigned int*)g,
      (__attribute__((address_space(3))) unsigned int*)l,
      16, 0, 0);
}

__device__ __forceinline__ float4v mfma_bf16(short8 a, short8 b, float4v c) {
  return __builtin_amdgcn_mfma_f32_16x16x32_bf16(a, b, c, 0, 0, 0);
}

__device__ __forceinline__ float16v mfma32(short8 a, short8 b, float16v c) {
  return __builtin_amdgcn_mfma_f32_32x32x16_bf16(a, b, c, 0, 0, 0);
}

__device__ __forceinline__ unsigned pack_bf16(float a, float b) {
  unsigned r;
  asm("v_cvt_pk_bf16_f32 %0, %1, %2" : "=v"(r) : "v"(a), "v"(b));
  return r;
}

// half-swap exchange: build PV A-fragment (8 contiguous keys per lane) from the
// C/D-pattern packed P pairs. hi = lane>>5.
__device__ __forceinline__ short8 xchg_p(unsigned p0, unsigned p1, unsigned p2,
                                         unsigned p3, int hi) {
  unsigned q0 = __shfl_xor(p0, 32);
  unsigned q1 = __shfl_xor(p1, 32);
  unsigned q2 = __shfl_xor(p2, 32);
  unsigned q3 = __shfl_xor(p3, 32);
  union { unsigned u[4]; short8 s; } t;
  t.u[0] = hi ? q2 : p0;
  t.u[1] = hi ? q3 : p1;
  t.u[2] = hi ? p2 : q0;
  t.u[3] = hi ? p3 : q1;
  return t.s;
}

// ---------------------------------------------------------------- f32 -> bf16

__global__ __launch_bounds__(256) void cvt_f32_bf16(const float* __restrict__ src,
                                                    bf16* __restrict__ dst, int n) {
  int i = (blockIdx.x * 256 + threadIdx.x) * 4;
  if (i + 3 < n) {
    float4 v = *reinterpret_cast<const float4*>(src + i);
    dst[i + 0] = __float2bfloat16(v.x);
    dst[i + 1] = __float2bfloat16(v.y);
    dst[i + 2] = __float2bfloat16(v.z);
    dst[i + 3] = __float2bfloat16(v.w);
  }
}

// ---------------------------------------------------------------- GEMM (C = A * B^T)
// 128x128 tile, BK=64, 4 waves (2x2 of 64x64), XOR-swizzled LDS, global_load_lds.

__global__ __launch_bounds__(256) void gemm_bt(const bf16* __restrict__ A,
                                               const bf16* __restrict__ B,
                                               float* __restrict__ C,
                                               int N, int K) {
  const int m0 = blockIdx.y * 128;
  const int n0 = blockIdx.x * 128;
  const int tid = threadIdx.x;
  const int l = tid & 63;
  const int w = tid >> 6;
  const int lg = l >> 4;
  const int li = l & 15;
  const int wr = (w >> 1) * 64;
  const int wc = (w & 1) * 64;

  __shared__ __align__(16) bf16 As[128][64];
  __shared__ __align__(16) bf16 Bs[128][64];

  float4v acc[4][4];
#pragma unroll
  for (int i = 0; i < 4; ++i)
#pragma unroll
    for (int j = 0; j < 4; ++j) acc[i][j] = (float4v)0.0f;

  const int srow = w * 32 + (l >> 3);
  const int scol = ((l & 7) ^ ((l >> 3) & 7)) * 8;
  const bf16* ga = A + (size_t)(m0 + srow) * K + scol;
  const bf16* gb = B + (size_t)(n0 + srow) * K + scol;
  bf16* la = &As[0][0] + w * 2048;
  bf16* lb = &Bs[0][0] + w * 2048;

  for (int kt = 0; kt < K; kt += 64) {
    __syncthreads();
#pragma unroll
    for (int j = 0; j < 4; ++j) {
      gload_lds16(ga + (size_t)j * 8 * K + kt, la + j * 512);
      gload_lds16(gb + (size_t)j * 8 * K + kt, lb + j * 512);
    }
    __syncthreads();

#pragma unroll
    for (int ks = 0; ks < 2; ++ks) {
      short8 a[4], b[4];
#pragma unroll
      for (int mt = 0; mt < 4; ++mt)
        a[mt] = *reinterpret_cast<const short8*>(
            &As[wr + mt * 16 + li][((ks * 4 + lg) ^ (li & 7)) * 8]);
#pragma unroll
      for (int nt = 0; nt < 4; ++nt)
        b[nt] = *reinterpret_cast<const short8*>(
            &Bs[wc + nt * 16 + li][((ks * 4 + lg) ^ (li & 7)) * 8]);
#pragma unroll
      for (int mt = 0; mt < 4; ++mt)
#pragma unroll
        for (int nt = 0; nt < 4; ++nt)
          acc[mt][nt] = mfma_bf16(a[mt], b[nt], acc[mt][nt]);
    }
  }

#pragma unroll
  for (int mt = 0; mt < 4; ++mt) {
    const int row = m0 + wr + mt * 16 + lg * 4;
#pragma unroll
    for (int nt = 0; nt < 4; ++nt) {
      const int col = n0 + wc + nt * 16 + li;
      float* cp = C + (size_t)row * N + col;
#pragma unroll
      for (int r = 0; r < 4; ++r) cp[(size_t)r * N] = acc[mt][nt][r];
    }
  }
}

// ---------------------------------------------------------------- bias + RoPE + cast
// Q is pre-scaled by HD^-0.5 * log2(e) (softmax done in base-2 domain).

#define QSCALE 0.12753588594439120f  // 128^-0.5 * log2(e)

__global__ __launch_bounds__(256) void rope_kernel(const float* __restrict__ qkv,
                                                   const float* __restrict__ bias,
                                                   const int* __restrict__ pos,
                                                   bf16* __restrict__ Qo,
                                                   bf16* __restrict__ Ko,
                                                   bf16* __restrict__ Vto) {
  const int t = blockIdx.x;
  const int tid = threadIdx.x;
  __shared__ float cs[64], sn[64];
  if (tid < 64) {
    float inv = powf(ROPE_THETA, -(2.0f * (float)tid) / (float)HD);
    float fr = (float)pos[t] * inv;
    float s, c;
    sincosf(fr, &s, &c);
    cs[tid] = c;
    sn[tid] = s;
  }
  __syncthreads();

  const float* row = qkv + (size_t)t * QKV_N;

  for (int idx = tid; idx < NH * 64; idx += 256) {
    int hh = idx >> 6, i = idx & 63;
    float x1 = row[hh * 128 + i] + bias[hh * 128 + i];
    float x2 = row[hh * 128 + 64 + i] + bias[hh * 128 + 64 + i];
    bf16* q = Qo + ((size_t)hh * T_SEQ + t) * HD;
    q[i] = __float2bfloat16((x1 * cs[i] - x2 * sn[i]) * QSCALE);
    q[64 + i] = __float2bfloat16((x2 * cs[i] + x1 * sn[i]) * QSCALE);
  }
  for (int idx = tid; idx < NKV * 64; idx += 256) {
    int hh = idx >> 6, i = idx & 63;
    float x1 = row[NH * 128 + hh * 128 + i] + bias[NH * 128 + hh * 128 + i];
    float x2 = row[NH * 128 + hh * 128 + 64 + i] + bias[NH * 128 + hh * 128 + 64 + i];
    bf16* k = Ko + ((size_t)hh * T_SEQ + t) * HD;
    k[i] = __float2bfloat16(x1 * cs[i] - x2 * sn[i]);
    k[64 + i] = __float2bfloat16(x2 * cs[i] + x1 * sn[i]);
  }
  for (int idx = tid; idx < NKV * HD; idx += 256) {
    int hh = idx >> 7, d = idx & 127;
    float x = row[(NH + NKV) * 128 + idx] + bias[(NH + NKV) * 128 + idx];
    Vto[((size_t)hh * HD + d) * T_SEQ + t] = __float2bfloat16(x);
  }
}

// ---------------------------------------------------------------- flash attention
// 32x32 swapped-QK^T form: S = K·Q^T so each lane's S values all belong to one
// q-row (col = lane&31). Softmax is in-lane + one shfl_xor(32). P goes to the PV
// A-fragment in-register (cvt_pk + half-swap shuffles). 4 waves x 32 q-rows
// (QB=128), KVB=64 double-buffered, defer-max, deferred denominator.

#define QB 128
#define KVB 64
#define DEFER_THR 8.0f

__global__ __launch_bounds__(256) void attn_kernel(const bf16* __restrict__ Q,
                                                   const bf16* __restrict__ K,
                                                   const bf16* __restrict__ Vt_g,
                                                   bf16* __restrict__ O) {
  const int h = blockIdx.y;
  // heavy-first, flipped per KV-group so co-resident pairs balance (heavy+light)
  const int qi = (h < 8) ? (31 - (int)blockIdx.x) : (int)blockIdx.x;
  const int qb0 = qi * QB;
  const int kvh = h / GQ;
  const int tid = threadIdx.x;
  const int l = tid & 63;
  const int w = tid >> 6;
  const int hi = l >> 5;
  const int l31 = l & 31;
  const int l7 = l & 7;

  __shared__ __align__(16) bf16 Ks[2][KVB][HD];   // 32 KB, col-block g stored at g^(row&7)
  __shared__ __align__(16) bf16 Vs[2][HD][KVB];   // 32 KB (V^T), col-block g at g^(d&7)

  // staging sources (pre-swizzled global, linear LDS dest) — same as prev round
  const bf16* gke = K + ((size_t)kvh * T_SEQ + w * 16 + (l >> 4)) * HD +
                    (((l & 15) ^ (l >> 4)) * 8);
  const bf16* gko = K + ((size_t)kvh * T_SEQ + w * 16 + (l >> 4)) * HD +
                    (((l & 15) ^ (4 + (l >> 4))) * 8);
  const bf16* gv = Vt_g + ((size_t)kvh * HD + w * 32 + (l >> 3)) * T_SEQ +
                   (((l & 7) ^ ((l >> 3) & 7)) * 8);
  bf16* lk = &Ks[0][0][0] + w * 2048;
  bf16* lv = &Vs[0][0][0] + w * 2048;

  const int nkb = 2 * qi + 2;

  // prologue: stage kb=0 into buffer 0
#pragma unroll
  for (int j = 0; j < 4; ++j) {
    const bf16* gkj = ((j & 1) ? gko : gke) + (size_t)(j * 4) * HD;
    gload_lds16(gkj, lk + j * 512);
    gload_lds16(gv + (size_t)j * 8 * T_SEQ, lv + j * 512);
  }

  // Q fragments: B-operand of S = K·Q^T. Lane holds q-col = l31, d = ks*16+hi*8+e.
  const int qw = qb0 + w * 32;
  const int qrow = qw + l31;
  short8 aq[8];
#pragma unroll
  for (int ks = 0; ks < 8; ++ks)
    aq[ks] = *reinterpret_cast<const short8*>(
        Q + ((size_t)h * T_SEQ + qrow) * HD + ks * 16 + hi * 8);

  float16v oacc[4];
#pragma unroll
  for (int dt = 0; dt < 4; ++dt) oacc[dt] = (float16v)0.0f;
  float m_run = -INFINITY;
  float l_part = 0.0f;

  asm volatile("s_waitcnt vmcnt(0)" ::: "memory");
  __syncthreads();

  for (int kb = 0; kb < nkb; ++kb) {
    const int cur = kb & 1;
    const int nxt = cur ^ 1;
    const int kb0 = kb * KVB;

    // async prefetch of next K/V tile
    if (kb + 1 < nkb) {
      const int kb0n = kb0 + KVB;
#pragma unroll
      for (int j = 0; j < 4; ++j) {
        const bf16* gkj = ((j & 1) ? gko : gke) + (size_t)(kb0n + j * 4) * HD;
        gload_lds16(gkj, lk + nxt * 8192 + j * 512);
        gload_lds16(gv + (size_t)j * 8 * T_SEQ + kb0n, lv + nxt * 8192 + j * 512);
      }
    }

    // S tiles: s0 = keys kb0+0..31, s1 = keys kb0+32..63 (all for q = l31 col)
    float16v s0 = (float16v)0.0f, s1 = (float16v)0.0f;
#pragma unroll
    for (int ks = 0; ks < 8; ++ks) {
      short8 k0 = *reinterpret_cast<const short8*>(
          &Ks[cur][l31][((ks * 2 + hi) ^ l7) * 8]);
      short8 k1 = *reinterpret_cast<const short8*>(
          &Ks[cur][32 + l31][((ks * 2 + hi) ^ l7) * 8]);
      s0 = mfma32(k0, aq[ks], s0);
      s1 = mfma32(k1, aq[ks], s1);
    }

    // causal mask (only near-diagonal tiles)
    if (kb0 + 63 > qw) {
      const int qg = qw + l31;
#pragma unroll
      for (int r = 0; r < 16; ++r) {
        const int key = kb0 + (r & 3) + 8 * (r >> 2) + 4 * hi;
        if (key > qg) s0[r] = -INFINITY;
        if (key + 32 > qg) s1[r] = -INFINITY;
      }
    }

    // in-lane max + pair exchange
    float mx = fmaxf(s0[0], s1[0]);
#pragma unroll
    for (int r = 1; r < 16; ++r) mx = fmaxf(mx, fmaxf(s0[r], s1[r]));
    mx = fmaxf(mx, __shfl_xor(mx, 32));

    // defer-max rescale (rare)
    if (__any(mx > m_run + DEFER_THR)) {
      const float mnew = fmaxf(m_run, mx);
      const float alpha = exp2f(m_run - mnew);
      m_run = mnew;
      l_part *= alpha;
#pragma unroll
      for (int r = 0; r < 16; ++r) {
        const float ar = __shfl(alpha, (r & 3) + 8 * (r >> 2) + 4 * hi);
#pragma unroll
        for (int dt = 0; dt < 4; ++dt) oacc[dt][r] *= ar;
      }
    }

    // P = exp2(S - m); pack to bf16 pairs; build PV A-fragments
    unsigned Pk[8];
#pragma unroll
    for (int i = 0; i < 8; ++i) {
      float a = exp2f(s0[2 * i] - m_run);
      float b = exp2f(s0[2 * i + 1] - m_run);
      l_part += a + b;
      Pk[i] = pack_bf16(a, b);
    }
    short8 pa0 = xchg_p(Pk[0], Pk[1], Pk[2], Pk[3], hi);
    short8 pa1 = xchg_p(Pk[4], Pk[5], Pk[6], Pk[7], hi);
#pragma unroll
    for (int i = 0; i < 8; ++i) {
      float a = exp2f(s1[2 * i] - m_run);
      float b = exp2f(s1[2 * i + 1] - m_run);
      l_part += a + b;
      Pk[i] = pack_bf16(a, b);
    }
    short8 pa2 = xchg_p(Pk[0], Pk[1], Pk[2], Pk[3], hi);
    short8 pa3 = xchg_p(Pk[4], Pk[5], Pk[6], Pk[7], hi);

    // O += P·V : A = P fragment, B = V^T from LDS (col = d = dt*32+l31)
#pragma unroll
    for (int dt = 0; dt < 4; ++dt) {
      short8 bv0 = *reinterpret_cast<const short8*>(
          &Vs[cur][dt * 32 + l31][((0 ^ (2 * 0 + hi)) ^ l7) * 8]);
      oacc[dt] = mfma32(pa0, bv0, oacc[dt]);
    }
#pragma unroll
    for (int dt = 0; dt < 4; ++dt) {
      short8 bv = *reinterpret_cast<const short8*>(
          &Vs[cur][dt * 32 + l31][((2 + hi) ^ l7) * 8]);
      oacc[dt] = mfma32(pa1, bv, oacc[dt]);
    }
#pragma unroll
    for (int dt = 0; dt < 4; ++dt) {
      short8 bv = *reinterpret_cast<const short8*>(
          &Vs[cur][dt * 32 + l31][((4 + hi) ^ l7) * 8]);
      oacc[dt] = mfma32(pa2, bv, oacc[dt]);
    }
#pragma unroll
    for (int dt = 0; dt < 4; ++dt) {
      short8 bv = *reinterpret_cast<const short8*>(
          &Vs[cur][dt * 32 + l31][((6 + hi) ^ l7) * 8]);
      oacc[dt] = mfma32(pa3, bv, oacc[dt]);
    }

    // prefetch done + all waves finished reading `cur`
    asm volatile("s_waitcnt vmcnt(0)" ::: "memory");
    __syncthreads();
  }

  // epilogue: pair-sum denominator, redistribute inverse to C/D rows, write O
  const float lt = l_part + __shfl_xor(l_part, 32);
  const float inv = 1.0f / lt;
#pragma unroll
  for (int r = 0; r < 16; ++r) {
    const int crow = (r & 3) + 8 * (r >> 2) + 4 * hi;
    const float ivr = __shfl(inv, crow);
    const int t = qw + crow;
    bf16* op = O + (size_t)t * (NH * HD) + h * HD + l31;
#pragma unroll
    for (int dt = 0; dt < 4; ++dt)
      op[dt * 32] = __float2bfloat16(oacc[dt][r] * ivr);
  }
}

// ---------------------------------------------------------------- launch

extern "C" void kernel_launch(void* const* d_in, const int* in_sizes, int n_in,
                              void* d_out, int out_size, void* d_ws, size_t ws_size,
                              hipStream_t stream) {
  const int* positions = (const int*)d_in[0];
  const float* hidden = (const float*)d_in[1];
  const float* w_qkv = (const float*)d_in[2];
  const float* b_qkv = (const float*)d_in[3];
  const float* w_o = (const float*)d_in[4];
  float* out = (float*)d_out;

  char* ws = (char*)d_ws;
  bf16* hs_bf = (bf16*)ws;   ws += (size_t)T_SEQ * HIDDEN * 2;
  bf16* wqkv_bf = (bf16*)ws; ws += (size_t)QKV_N * HIDDEN * 2;
  bf16* wo_bf = (bf16*)ws;   ws += (size_t)HIDDEN * HIDDEN * 2;
  float* qkv_f = (float*)ws; ws += (size_t)T_SEQ * QKV_N * 4;
  bf16* q_bf = (bf16*)ws;    ws += (size_t)NH * T_SEQ * HD * 2;
  bf16* k_bf = (bf16*)ws;    ws += (size_t)NKV * T_SEQ * HD * 2;
  bf16* vt_bf = (bf16*)ws;   ws += (size_t)NKV * T_SEQ * HD * 2;
  bf16* attn_bf = (bf16*)ws; ws += (size_t)T_SEQ * HIDDEN * 2;

  cvt_f32_bf16<<<(T_SEQ * HIDDEN) / 1024, 256, 0, stream>>>(hidden, hs_bf, T_SEQ * HIDDEN);
  cvt_f32_bf16<<<(QKV_N * HIDDEN) / 1024, 256, 0, stream>>>(w_qkv, wqkv_bf, QKV_N * HIDDEN);
  cvt_f32_bf16<<<(HIDDEN * HIDDEN) / 1024, 256, 0, stream>>>(w_o, wo_bf, HIDDEN * HIDDEN);

  gemm_bt<<<dim3(QKV_N / 128, T_SEQ / 128), 256, 0, stream>>>(hs_bf, wqkv_bf, qkv_f,
                                                              QKV_N, HIDDEN);

  rope_kernel<<<T_SEQ, 256, 0, stream>>>(qkv_f, b_qkv, positions, q_bf, k_bf, vt_bf);

  attn_kernel<<<dim3(T_SEQ / QB, NH), 256, 0, stream>>>(q_bf, k_bf, vt_bf, attn_bf);

  gemm_bt<<<dim3(HIDDEN / 128, T_SEQ / 128), 256, 0, stream>>>(attn_bf, wo_bf, out,
                                                               HIDDEN, HIDDEN);
}

// Round 5
// 425.961 us; speedup vs baseline: 1.2706x; 1.2706x over previous
//
#include <hip/hip_runtime.h>
#include <hip/hip_bf16.h>
#include <math.h>

#define T_SEQ 4096
#define HIDDEN 2048
#define NH 16
#define NKV 2
#define HD 128
#define GQ (NH / NKV)
#define QKV_N 2560
#define ROPE_THETA 10000.0f

using bf16 = __hip_bfloat16;
typedef __attribute__((ext_vector_type(8))) short short8;
typedef __attribute__((ext_vector_type(4))) float float4v;
typedef __attribute__((ext_vector_type(16))) float float16v;

// ---------------------------------------------------------------- helpers

__device__ __forceinline__ void gload_lds16(const void* g, void* l) {
  __builtin_amdgcn_global_load_lds(
      (const __attribute__((address_space(1))) unsigned int*)g,
      (__attribute__((address_space(3))) unsigned int*)l,
      16, 0, 0);
}

__device__ __forceinline__ float4v mfma_bf16(short8 a, short8 b, float4v c) {
  return __builtin_amdgcn_mfma_f32_16x16x32_bf16(a, b, c, 0, 0, 0);
}

__device__ __forceinline__ float16v mfma32(short8 a, short8 b, float16v c) {
  return __builtin_amdgcn_mfma_f32_32x32x16_bf16(a, b, c, 0, 0, 0);
}

__device__ __forceinline__ unsigned pack_bf16(float a, float b) {
  unsigned r;
  asm("v_cvt_pk_bf16_f32 %0, %1, %2" : "=v"(r) : "v"(a), "v"(b));
  return r;
}

// half-swap exchange: build PV A-fragment (8 contiguous keys per lane) from the
// C/D-pattern packed P pairs. hi = lane>>5.
__device__ __forceinline__ short8 xchg_p(unsigned p0, unsigned p1, unsigned p2,
                                         unsigned p3, int hi) {
  unsigned q0 = __shfl_xor(p0, 32);
  unsigned q1 = __shfl_xor(p1, 32);
  unsigned q2 = __shfl_xor(p2, 32);
  unsigned q3 = __shfl_xor(p3, 32);
  union { unsigned u[4]; short8 s; } t;
  t.u[0] = hi ? q2 : p0;
  t.u[1] = hi ? q3 : p1;
  t.u[2] = hi ? p2 : q0;
  t.u[3] = hi ? p3 : q1;
  return t.s;
}

// ---------------------------------------------------------------- f32 -> bf16

__global__ __launch_bounds__(256) void cvt_f32_bf16(const float* __restrict__ src,
                                                    bf16* __restrict__ dst, int n) {
  int i = (blockIdx.x * 256 + threadIdx.x) * 4;
  if (i + 3 < n) {
    float4 v = *reinterpret_cast<const float4*>(src + i);
    dst[i + 0] = __float2bfloat16(v.x);
    dst[i + 1] = __float2bfloat16(v.y);
    dst[i + 2] = __float2bfloat16(v.z);
    dst[i + 3] = __float2bfloat16(v.w);
  }
}

// ---------------------------------------------------------------- GEMM (C = A * B^T)
// 128x128 tile, BK=64, 4 waves (2x2 of 64x64), XOR-swizzled LDS, global_load_lds.

__global__ __launch_bounds__(256) void gemm_bt(const bf16* __restrict__ A,
                                               const bf16* __restrict__ B,
                                               float* __restrict__ C,
                                               int N, int K) {
  const int m0 = blockIdx.y * 128;
  const int n0 = blockIdx.x * 128;
  const int tid = threadIdx.x;
  const int l = tid & 63;
  const int w = tid >> 6;
  const int lg = l >> 4;
  const int li = l & 15;
  const int wr = (w >> 1) * 64;
  const int wc = (w & 1) * 64;

  __shared__ __align__(16) bf16 As[128][64];
  __shared__ __align__(16) bf16 Bs[128][64];

  float4v acc[4][4];
#pragma unroll
  for (int i = 0; i < 4; ++i)
#pragma unroll
    for (int j = 0; j < 4; ++j) acc[i][j] = (float4v)0.0f;

  const int srow = w * 32 + (l >> 3);
  const int scol = ((l & 7) ^ ((l >> 3) & 7)) * 8;
  const bf16* ga = A + (size_t)(m0 + srow) * K + scol;
  const bf16* gb = B + (size_t)(n0 + srow) * K + scol;
  bf16* la = &As[0][0] + w * 2048;
  bf16* lb = &Bs[0][0] + w * 2048;

  for (int kt = 0; kt < K; kt += 64) {
    __syncthreads();
#pragma unroll
    for (int j = 0; j < 4; ++j) {
      gload_lds16(ga + (size_t)j * 8 * K + kt, la + j * 512);
      gload_lds16(gb + (size_t)j * 8 * K + kt, lb + j * 512);
    }
    __syncthreads();

#pragma unroll
    for (int ks = 0; ks < 2; ++ks) {
      short8 a[4], b[4];
#pragma unroll
      for (int mt = 0; mt < 4; ++mt)
        a[mt] = *reinterpret_cast<const short8*>(
            &As[wr + mt * 16 + li][((ks * 4 + lg) ^ (li & 7)) * 8]);
#pragma unroll
      for (int nt = 0; nt < 4; ++nt)
        b[nt] = *reinterpret_cast<const short8*>(
            &Bs[wc + nt * 16 + li][((ks * 4 + lg) ^ (li & 7)) * 8]);
#pragma unroll
      for (int mt = 0; mt < 4; ++mt)
#pragma unroll
        for (int nt = 0; nt < 4; ++nt)
          acc[mt][nt] = mfma_bf16(a[mt], b[nt], acc[mt][nt]);
    }
  }

#pragma unroll
  for (int mt = 0; mt < 4; ++mt) {
    const int row = m0 + wr + mt * 16 + lg * 4;
#pragma unroll
    for (int nt = 0; nt < 4; ++nt) {
      const int col = n0 + wc + nt * 16 + li;
      float* cp = C + (size_t)row * N + col;
#pragma unroll
      for (int r = 0; r < 4; ++r) cp[(size_t)r * N] = acc[mt][nt][r];
    }
  }
}

// ---------------------------------------------------------------- bias + RoPE + cast
// Q is pre-scaled by HD^-0.5 * log2(e) (softmax done in base-2 domain).

#define QSCALE 0.12753588594439120f  // 128^-0.5 * log2(e)

__global__ __launch_bounds__(256) void rope_kernel(const float* __restrict__ qkv,
                                                   const float* __restrict__ bias,
                                                   const int* __restrict__ pos,
                                                   bf16* __restrict__ Qo,
                                                   bf16* __restrict__ Ko,
                                                   bf16* __restrict__ Vto) {
  const int t = blockIdx.x;
  const int tid = threadIdx.x;
  __shared__ float cs[64], sn[64];
  if (tid < 64) {
    float inv = powf(ROPE_THETA, -(2.0f * (float)tid) / (float)HD);
    float fr = (float)pos[t] * inv;
    float s, c;
    sincosf(fr, &s, &c);
    cs[tid] = c;
    sn[tid] = s;
  }
  __syncthreads();

  const float* row = qkv + (size_t)t * QKV_N;

  for (int idx = tid; idx < NH * 64; idx += 256) {
    int hh = idx >> 6, i = idx & 63;
    float x1 = row[hh * 128 + i] + bias[hh * 128 + i];
    float x2 = row[hh * 128 + 64 + i] + bias[hh * 128 + 64 + i];
    bf16* q = Qo + ((size_t)hh * T_SEQ + t) * HD;
    q[i] = __float2bfloat16((x1 * cs[i] - x2 * sn[i]) * QSCALE);
    q[64 + i] = __float2bfloat16((x2 * cs[i] + x1 * sn[i]) * QSCALE);
  }
  for (int idx = tid; idx < NKV * 64; idx += 256) {
    int hh = idx >> 6, i = idx & 63;
    float x1 = row[NH * 128 + hh * 128 + i] + bias[NH * 128 + hh * 128 + i];
    float x2 = row[NH * 128 + hh * 128 + 64 + i] + bias[NH * 128 + hh * 128 + 64 + i];
    bf16* k = Ko + ((size_t)hh * T_SEQ + t) * HD;
    k[i] = __float2bfloat16(x1 * cs[i] - x2 * sn[i]);
    k[64 + i] = __float2bfloat16(x2 * cs[i] + x1 * sn[i]);
  }
  for (int idx = tid; idx < NKV * HD; idx += 256) {
    int hh = idx >> 7, d = idx & 127;
    float x = row[(NH + NKV) * 128 + idx] + bias[(NH + NKV) * 128 + idx];
    Vto[((size_t)hh * HD + d) * T_SEQ + t] = __float2bfloat16(x);
  }
}

// ---------------------------------------------------------------- flash attention
// 32x32 swapped-QK^T form (S = K·Q^T, softmax in-lane + one shfl_xor(32), P built
// in-register). LOAD-BALANCED: each block processes TWO q-tiles (31-bx and bx),
// so every block does exactly 68 kb-iterations -> 256 equal blocks, 1 per CU.

#define QB 128
#define KVB 64
#define DEFER_THR 8.0f

__global__ __launch_bounds__(256) void attn_kernel(const bf16* __restrict__ Q,
                                                   const bf16* __restrict__ K,
                                                   const bf16* __restrict__ Vt_g,
                                                   bf16* __restrict__ O) {
  const int h = blockIdx.y;
  const int kvh = h / GQ;
  const int bx = blockIdx.x;  // 0..15
  const int tid = threadIdx.x;
  const int l = tid & 63;
  const int w = tid >> 6;
  const int hi = l >> 5;
  const int l31 = l & 31;
  const int l7 = l & 7;

  __shared__ __align__(16) bf16 Ks[2][KVB][HD];   // 32 KB, col-block g stored at g^(row&7)
  __shared__ __align__(16) bf16 Vs[2][HD][KVB];   // 32 KB (V^T), col-block g at g^(d&7)

  // staging sources (pre-swizzled global, linear LDS dest)
  const bf16* gke = K + ((size_t)kvh * T_SEQ + w * 16 + (l >> 4)) * HD +
                    (((l & 15) ^ (l >> 4)) * 8);
  const bf16* gko = K + ((size_t)kvh * T_SEQ + w * 16 + (l >> 4)) * HD +
                    (((l & 15) ^ (4 + (l >> 4))) * 8);
  const bf16* gv = Vt_g + ((size_t)kvh * HD + w * 32 + (l >> 3)) * T_SEQ +
                   (((l & 7) ^ ((l >> 3) & 7)) * 8);
  bf16* lk = &Ks[0][0][0] + w * 2048;
  bf16* lv = &Vs[0][0][0] + w * 2048;

  for (int pass = 0; pass < 2; ++pass) {
    const int qi = pass ? bx : (31 - bx);  // pair (31-bx, bx): equal total work
    const int qb0 = qi * QB;
    const int nkb = 2 * qi + 2;
    const int qw = qb0 + w * 32;

    // prologue: stage kb=0 into buffer 0 (previous pass ended with a barrier)
#pragma unroll
    for (int j = 0; j < 4; ++j) {
      const bf16* gkj = ((j & 1) ? gko : gke) + (size_t)(j * 4) * HD;
      gload_lds16(gkj, lk + j * 512);
      gload_lds16(gv + (size_t)j * 8 * T_SEQ, lv + j * 512);
    }

    // Q fragments: B-operand of S = K·Q^T. Lane holds q-col = l31, d = ks*16+hi*8+e.
    const int qrow = qw + l31;
    short8 aq[8];
#pragma unroll
    for (int ks = 0; ks < 8; ++ks)
      aq[ks] = *reinterpret_cast<const short8*>(
          Q + ((size_t)h * T_SEQ + qrow) * HD + ks * 16 + hi * 8);

    float16v oacc[4];
#pragma unroll
    for (int dt = 0; dt < 4; ++dt) oacc[dt] = (float16v)0.0f;
    float m_run = -INFINITY;
    float l_part = 0.0f;

    asm volatile("s_waitcnt vmcnt(0)" ::: "memory");
    __syncthreads();

    for (int kb = 0; kb < nkb; ++kb) {
      const int cur = kb & 1;
      const int nxt = cur ^ 1;
      const int kb0 = kb * KVB;

      // async prefetch of next K/V tile
      if (kb + 1 < nkb) {
        const int kb0n = kb0 + KVB;
#pragma unroll
        for (int j = 0; j < 4; ++j) {
          const bf16* gkj = ((j & 1) ? gko : gke) + (size_t)(kb0n + j * 4) * HD;
          gload_lds16(gkj, lk + nxt * 8192 + j * 512);
          gload_lds16(gv + (size_t)j * 8 * T_SEQ + kb0n, lv + nxt * 8192 + j * 512);
        }
      }

      // S tiles: s0 = keys kb0+0..31, s1 = keys kb0+32..63 (all for q-col = l31)
      float16v s0 = (float16v)0.0f, s1 = (float16v)0.0f;
#pragma unroll
      for (int ks = 0; ks < 8; ++ks) {
        short8 k0 = *reinterpret_cast<const short8*>(
            &Ks[cur][l31][((ks * 2 + hi) ^ l7) * 8]);
        short8 k1 = *reinterpret_cast<const short8*>(
            &Ks[cur][32 + l31][((ks * 2 + hi) ^ l7) * 8]);
        s0 = mfma32(k0, aq[ks], s0);
        s1 = mfma32(k1, aq[ks], s1);
      }

      // causal mask (only near-diagonal tiles)
      if (kb0 + 63 > qw) {
        const int qg = qw + l31;
#pragma unroll
        for (int r = 0; r < 16; ++r) {
          const int key = kb0 + (r & 3) + 8 * (r >> 2) + 4 * hi;
          if (key > qg) s0[r] = -INFINITY;
          if (key + 32 > qg) s1[r] = -INFINITY;
        }
      }

      // in-lane max + pair exchange
      float mx = fmaxf(s0[0], s1[0]);
#pragma unroll
      for (int r = 1; r < 16; ++r) mx = fmaxf(mx, fmaxf(s0[r], s1[r]));
      mx = fmaxf(mx, __shfl_xor(mx, 32));

      // defer-max rescale (rare)
      if (__any(mx > m_run + DEFER_THR)) {
        const float mnew = fmaxf(m_run, mx);
        const float alpha = exp2f(m_run - mnew);
        m_run = mnew;
        l_part *= alpha;
#pragma unroll
        for (int r = 0; r < 16; ++r) {
          const float ar = __shfl(alpha, (r & 3) + 8 * (r >> 2) + 4 * hi);
#pragma unroll
          for (int dt = 0; dt < 4; ++dt) oacc[dt][r] *= ar;
        }
      }

      // P = exp2(S - m); pack to bf16 pairs; build PV A-fragments
      unsigned Pk[8];
#pragma unroll
      for (int i = 0; i < 8; ++i) {
        float a = exp2f(s0[2 * i] - m_run);
        float b = exp2f(s0[2 * i + 1] - m_run);
        l_part += a + b;
        Pk[i] = pack_bf16(a, b);
      }
      short8 pa0 = xchg_p(Pk[0], Pk[1], Pk[2], Pk[3], hi);
      short8 pa1 = xchg_p(Pk[4], Pk[5], Pk[6], Pk[7], hi);
#pragma unroll
      for (int i = 0; i < 8; ++i) {
        float a = exp2f(s1[2 * i] - m_run);
        float b = exp2f(s1[2 * i + 1] - m_run);
        l_part += a + b;
        Pk[i] = pack_bf16(a, b);
      }
      short8 pa2 = xchg_p(Pk[0], Pk[1], Pk[2], Pk[3], hi);
      short8 pa3 = xchg_p(Pk[4], Pk[5], Pk[6], Pk[7], hi);

      // O += P·V : A = P fragment, B = V^T from LDS (col = d = dt*32+l31)
#pragma unroll
      for (int dt = 0; dt < 4; ++dt) {
        short8 bv = *reinterpret_cast<const short8*>(
            &Vs[cur][dt * 32 + l31][((0 + hi) ^ l7) * 8]);
        oacc[dt] = mfma32(pa0, bv, oacc[dt]);
      }
#pragma unroll
      for (int dt = 0; dt < 4; ++dt) {
        short8 bv = *reinterpret_cast<const short8*>(
            &Vs[cur][dt * 32 + l31][((2 + hi) ^ l7) * 8]);
        oacc[dt] = mfma32(pa1, bv, oacc[dt]);
      }
#pragma unroll
      for (int dt = 0; dt < 4; ++dt) {
        short8 bv = *reinterpret_cast<const short8*>(
            &Vs[cur][dt * 32 + l31][((4 + hi) ^ l7) * 8]);
        oacc[dt] = mfma32(pa2, bv, oacc[dt]);
      }
#pragma unroll
      for (int dt = 0; dt < 4; ++dt) {
        short8 bv = *reinterpret_cast<const short8*>(
            &Vs[cur][dt * 32 + l31][((6 + hi) ^ l7) * 8]);
        oacc[dt] = mfma32(pa3, bv, oacc[dt]);
      }

      // prefetch done + all waves finished reading `cur`
      asm volatile("s_waitcnt vmcnt(0)" ::: "memory");
      __syncthreads();
    }

    // epilogue: pair-sum denominator, redistribute inverse to C/D rows, write O
    const float lt = l_part + __shfl_xor(l_part, 32);
    const float inv = 1.0f / lt;
#pragma unroll
    for (int r = 0; r < 16; ++r) {
      const int crow = (r & 3) + 8 * (r >> 2) + 4 * hi;
      const float ivr = __shfl(inv, crow);
      const int t = qw + crow;
      bf16* op = O + (size_t)t * (NH * HD) + h * HD + l31;
#pragma unroll
      for (int dt = 0; dt < 4; ++dt)
        op[dt * 32] = __float2bfloat16(oacc[dt][r] * ivr);
    }
  }
}

// ---------------------------------------------------------------- launch

extern "C" void kernel_launch(void* const* d_in, const int* in_sizes, int n_in,
                              void* d_out, int out_size, void* d_ws, size_t ws_size,
                              hipStream_t stream) {
  const int* positions = (const int*)d_in[0];
  const float* hidden = (const float*)d_in[1];
  const float* w_qkv = (const float*)d_in[2];
  const float* b_qkv = (const float*)d_in[3];
  const float* w_o = (const float*)d_in[4];
  float* out = (float*)d_out;

  char* ws = (char*)d_ws;
  bf16* hs_bf = (bf16*)ws;   ws += (size_t)T_SEQ * HIDDEN * 2;
  bf16* wqkv_bf = (bf16*)ws; ws += (size_t)QKV_N * HIDDEN * 2;
  bf16* wo_bf = (bf16*)ws;   ws += (size_t)HIDDEN * HIDDEN * 2;
  float* qkv_f = (float*)ws; ws += (size_t)T_SEQ * QKV_N * 4;
  bf16* q_bf = (bf16*)ws;    ws += (size_t)NH * T_SEQ * HD * 2;
  bf16* k_bf = (bf16*)ws;    ws += (size_t)NKV * T_SEQ * HD * 2;
  bf16* vt_bf = (bf16*)ws;   ws += (size_t)NKV * T_SEQ * HD * 2;
  bf16* attn_bf = (bf16*)ws; ws += (size_t)T_SEQ * HIDDEN * 2;

  cvt_f32_bf16<<<(T_SEQ * HIDDEN) / 1024, 256, 0, stream>>>(hidden, hs_bf, T_SEQ * HIDDEN);
  cvt_f32_bf16<<<(QKV_N * HIDDEN) / 1024, 256, 0, stream>>>(w_qkv, wqkv_bf, QKV_N * HIDDEN);
  cvt_f32_bf16<<<(HIDDEN * HIDDEN) / 1024, 256, 0, stream>>>(w_o, wo_bf, HIDDEN * HIDDEN);

  gemm_bt<<<dim3(QKV_N / 128, T_SEQ / 128), 256, 0, stream>>>(hs_bf, wqkv_bf, qkv_f,
                                                              QKV_N, HIDDEN);

  rope_kernel<<<T_SEQ, 256, 0, stream>>>(qkv_f, b_qkv, positions, q_bf, k_bf, vt_bf);

  attn_kernel<<<dim3(T_SEQ / QB / 2, NH), 256, 0, stream>>>(q_bf, k_bf, vt_bf, attn_bf);

  gemm_bt<<<dim3(HIDDEN / 128, T_SEQ / 128), 256, 0, stream>>>(attn_bf, wo_bf, out,
                                                               HIDDEN, HIDDEN);
}